// Round 3
// baseline (173.730 us; speedup 1.0000x reference)
//
#include <hip/hip_runtime.h>
#include <hip/hip_bf16.h>

#define N_NODES 50000
#define N_EDGES 800000
#define D 64
#define CAP 64        // per-node edge-list capacity (mean in-degree 15, max ~40)
#define CHUNK_E 2048  // edges per scatter block
#define NSC 391       // ceil(800000/2048)
#define NSTRIP 3125   // N_NODES/16
#define GEMM_BLKS 782 // 782*4 waves = 3128 >= NSTRIP (1 strip/wave)
#define SETUP_BLKS 64

typedef __attribute__((ext_vector_type(8))) short short8v;   // 8 bf16 (4 VGPRs)
typedef __attribute__((ext_vector_type(4))) float float4v;   // 4 fp32 acc

// ---------- helpers ----------
__device__ __forceinline__ float b2f(unsigned short h) {
    return __uint_as_float(((unsigned)h) << 16);
}
__device__ __forceinline__ unsigned short f2b(float f) {
    __hip_bfloat16 t = __float2bfloat16(f);
    return *reinterpret_cast<unsigned short*>(&t);
}
__device__ __forceinline__ short f2bs(float f) { return (short)f2b(f); }

// ---------- kernel 1: setup: flags, W->bf16 W^T frags, bias, zero cnt ----------
// block 0: flags + fragments + bias; ALL blocks: zero the 50000-entry counter.
__global__ __launch_bounds__(256)
void setup(const void* __restrict__ featv, const void* __restrict__ srcv,
           const void* __restrict__ Wtv, const void* __restrict__ btv,
           const void* __restrict__ Wpv, const void* __restrict__ bpv,
           unsigned* __restrict__ flags, unsigned* __restrict__ cnt,
           unsigned short* __restrict__ WTfrag, unsigned short* __restrict__ WPfrag,
           float* __restrict__ bias_sum) {
    const int t = threadIdx.x;
    // zero per-node counters (all blocks)
    for (int i = blockIdx.x * 256 + t; i < N_NODES; i += SETUP_BLKS * 256) cnt[i] = 0;
    if (blockIdx.x != 0) return;

    __shared__ unsigned sf[2];
    if (t < 64) {
        const unsigned short* p = (const unsigned short*)featv;
        float x = b2f(p[2 * t]);
        float a = fabsf(x);
        bool insane = !(a <= 64.f) || (x != 0.f && a < 9.3132e-10f);
        unsigned long long m = __ballot(insane);
        if (t == 0) sf[0] = (__popcll(m) >= 8) ? 1u : 0u;
    } else if (t < 128) {
        const int* s32 = (const int*)srcv;
        int v = s32[2 * (t - 64) + 1];
        unsigned long long m = __ballot(v == 0);
        if (t == 64) sf[1] = (__popcll(m) >= 32) ? 1u : 0u;
    }
    __syncthreads();
    const unsigned fp32mode = sf[0];
    if (t < 2) flags[t] = sf[t];
#pragma unroll
    for (int i = 0; i < 16; ++i) {
        int e = i * 256 + t;                           // coalesced read
        int k = e >> 6, n = e & 63;
        float vt, vp;
        if (fp32mode) {
            vt = ((const float*)Wtv)[e];
            vp = ((const float*)Wpv)[e];
        } else {
            vt = b2f(((const unsigned short*)Wtv)[e]);
            vp = b2f(((const unsigned short*)Wpv)[e]);
        }
        WTfrag[n * 64 + k] = f2b(vt);                  // Wfrag[n*64+k] = W[k][n]
        WPfrag[n * 64 + k] = f2b(vp);
    }
    if (t < 64) {
        if (fp32mode)
            bias_sum[t] = ((const float*)btv)[t] + ((const float*)bpv)[t];
        else
            bias_sum[t] = b2f(((const unsigned short*)btv)[t])
                        + b2f(((const unsigned short*)bpv)[t]);
    }
}

// ---------- A(X)-fragment load helpers (strip w, lane m,q) ----------
__device__ __forceinline__ void loadA_bf16(const short* F, int w, int m, int q,
                                           short8v& A0, short8v& A1) {
    const short* fr = F + (w * 16 + m) * D + q * 8;
    A0 = *(const short8v*)fr;
    A1 = *(const short8v*)(fr + 32);
}
__device__ __forceinline__ void loadA_raw(const float* F, int w, int m, int q,
                                          float4 r[8]) {
    const float* fr = F + (w * 16 + m) * D + q * 8;
    r[0] = *(const float4*)(fr);      r[1] = *(const float4*)(fr + 4);
    r[2] = *(const float4*)(fr + 32); r[3] = *(const float4*)(fr + 36);
}
__device__ __forceinline__ void cvtA(const float4 r[8], short8v& A0, short8v& A1) {
    A0 = (short8v){f2bs(r[0].x), f2bs(r[0].y), f2bs(r[0].z), f2bs(r[0].w),
                   f2bs(r[1].x), f2bs(r[1].y), f2bs(r[1].z), f2bs(r[1].w)};
    A1 = (short8v){f2bs(r[2].x), f2bs(r[2].y), f2bs(r[2].z), f2bs(r[2].w),
                   f2bs(r[3].x), f2bs(r[3].y), f2bs(r[3].z), f2bs(r[3].w)};
}

// ---------- kernel 2: fused [MFMA node transforms ∥ per-node edge-list scatter] --
// gemm blocks [0, GEMM_BLKS): SWAPPED-operand MFMA: D[feat][node] so each lane
//   holds 4 CONSECUTIVE features of one node -> uint2/float4 stores (4x fewer
//   store instructions than the scalar-per-element D[node][feat] layout).
//   Fragment bytes are identical to the unswapped version (A/B per-lane layouts
//   are symmetric: row/col = lane&15, k = (lane>>4)*8+j); only the intrinsic
//   argument order changes. 1 strip/wave, 782 blocks -> real occupancy.
// blocks [GEMM_BLKS, +NSC): single-pass per-edge append into per-node CSR rows:
//   pos = atomicAdd(&cnt[d],1); packed16[d*CAP+pos] = src (u16, N_NODES<65536).
//   Self-loops dropped (node_min seeds with own T row).
__global__ __launch_bounds__(256)
void gemm_scatter(const void* __restrict__ featv,
                  const unsigned short* __restrict__ WTfrag,
                  const unsigned short* __restrict__ WPfrag,
                  const float* __restrict__ bias_sum,
                  const void* __restrict__ srcv, const void* __restrict__ dstv,
                  const unsigned* __restrict__ flags,
                  unsigned* __restrict__ cnt, unsigned short* __restrict__ packed16,
                  unsigned short* __restrict__ T16, void* __restrict__ outv) {
    const unsigned fp32mode = flags[0];
    if (blockIdx.x < GEMM_BLKS) {
        const int lane = threadIdx.x & 63;
        const int wid  = threadIdx.x >> 6;
        const int w = blockIdx.x * 4 + wid;            // strip 0..3127
        if (w >= NSTRIP) return;
        const int m = lane & 15, q = lane >> 4;

        // W fragments (L2-hot 16 KB) + per-(c,q) bias quad
        const short8v* BT = (const short8v*)WTfrag;    // idx = feat*8 + half*4 + q
        const short8v* BP = (const short8v*)WPfrag;
        short8v Bt0[4], Bt1[4], Bp0[4], Bp1[4];
        float4 bs4[4];
#pragma unroll
        for (int c = 0; c < 4; ++c) {
            const int col = 16 * c + m;
            Bt0[c] = BT[col * 8 + q];
            Bt1[c] = BT[col * 8 + 4 + q];
            Bp0[c] = BP[col * 8 + q];
            Bp1[c] = BP[col * 8 + 4 + q];
            bs4[c] = *(const float4*)(bias_sum + 16 * c + 4 * q);
        }

        short8v A0, A1;
        if (fp32mode) {
            float4 raw[8];
            loadA_raw((const float*)featv, w, m, q, raw);
            cvtA(raw, A0, A1);
        } else {
            loadA_bf16((const short*)featv, w, m, q, A0, A1);
        }

        const int node = w * 16 + m;
        unsigned short* Trow = T16 + node * D;
        float* Cf = (float*)outv + node * D;
        unsigned short* Ch = (unsigned short*)outv + node * D;
#pragma unroll
        for (int c = 0; c < 4; ++c) {
            float4v accT = (float4v){0.f, 0.f, 0.f, 0.f};
            float4v accP = (float4v){bs4[c].x, bs4[c].y, bs4[c].z, bs4[c].w};
            // swapped operands: D = W^T(frag) x X^T(frag) -> D[feat][node]
            accT = __builtin_amdgcn_mfma_f32_16x16x32_bf16(Bt0[c], A0, accT, 0, 0, 0);
            accT = __builtin_amdgcn_mfma_f32_16x16x32_bf16(Bt1[c], A1, accT, 0, 0, 0);
            accP = __builtin_amdgcn_mfma_f32_16x16x32_bf16(Bp0[c], A0, accP, 0, 0, 0);
            accP = __builtin_amdgcn_mfma_f32_16x16x32_bf16(Bp1[c], A1, accP, 0, 0, 0);
            // D layout: col(lane&15)=node-in-strip, row(q*4+r)=feat-in-chunk
            const int foff = 16 * c + 4 * q;           // 4 consecutive feats
            unsigned t0 = (unsigned)f2b(accT[0]) | ((unsigned)f2b(accT[1]) << 16);
            unsigned t1 = (unsigned)f2b(accT[2]) | ((unsigned)f2b(accT[3]) << 16);
            *(uint2*)(Trow + foff) = make_uint2(t0, t1);
            if (fp32mode) {
                *(float4*)(Cf + foff) = make_float4(accT[0] + accP[0], accT[1] + accP[1],
                                                    accT[2] + accP[2], accT[3] + accP[3]);
            } else {
                unsigned c0 = (unsigned)f2b(accT[0] + accP[0])
                            | ((unsigned)f2b(accT[1] + accP[1]) << 16);
                unsigned c1 = (unsigned)f2b(accT[2] + accP[2])
                            | ((unsigned)f2b(accT[3] + accP[3]) << 16);
                *(uint2*)(Ch + foff) = make_uint2(c0, c1);
            }
        }
    } else {
        // ---- per-node CSR append (single pass) ----
        const unsigned idx64 = flags[1];
        const int base = (blockIdx.x - GEMM_BLKS) * CHUNK_E;
        const int t = threadIdx.x;
#pragma unroll
        for (int j = 0; j < CHUNK_E / 256; ++j) {
            int e = base + j * 256 + t;
            if (e < N_EDGES) {
                int s, d;
                if (idx64) {
                    s = (int)((const long long*)srcv)[e];
                    d = (int)((const long long*)dstv)[e];
                } else {
                    s = ((const int*)srcv)[e];
                    d = ((const int*)dstv)[e];
                }
                s = min(max(s, 0), N_NODES - 1);
                d = min(max(d, 0), N_NODES - 1);
                if (s != d) {                          // self-loop covered by seed
                    unsigned pos = atomicAdd(&cnt[d], 1u);
                    if (pos < CAP)                     // overflow guard (P~0)
                        packed16[(unsigned)d * CAP + pos] = (unsigned short)s;
                }
            }
        }
    }
}

#define MIN8(vv)                                                     \
    do {                                                             \
        mn[0] = fminf(mn[0], b2f((unsigned short)(vv).x));           \
        mn[1] = fminf(mn[1], b2f((unsigned short)((vv).x >> 16)));   \
        mn[2] = fminf(mn[2], b2f((unsigned short)(vv).y));           \
        mn[3] = fminf(mn[3], b2f((unsigned short)((vv).y >> 16)));   \
        mn[4] = fminf(mn[4], b2f((unsigned short)(vv).z));           \
        mn[5] = fminf(mn[5], b2f((unsigned short)((vv).z >> 16)));   \
        mn[6] = fminf(mn[6], b2f((unsigned short)((vv).w)));         \
        mn[7] = fminf(mn[7], b2f((unsigned short)((vv).w >> 16)));   \
    } while (0)

// ---------- kernel 3: per-node register min + fused epilogue ----------
// 8 lanes per node (uint4 = 16 B/lane covers the 64-short T row), 32 nodes per
// 256-thr block, 1563 blocks. Running minima live in 8 VGPRs per lane — zero
// LDS, zero atomics. Seed = own T row (covers self-loops). 1-deep gather
// pipeline; 32 independent groups/block x ~4 blocks/CU hide L2 latency.
__global__ __launch_bounds__(256, 4)
void node_min(const unsigned* __restrict__ cnt, const unsigned short* __restrict__ packed16,
              const unsigned short* __restrict__ T16, const unsigned* __restrict__ flags,
              void* __restrict__ outv) {
    const unsigned fp32mode = flags[0];
    const int t = threadIdx.x;
    const int g = t >> 3, sub = t & 7;
    const int node = blockIdx.x * 32 + g;
    if (node >= N_NODES) return;
    const int fo = sub * 8;                            // short offset in row
    float mn[8];
    {
        uint4 v = *(const uint4*)(T16 + node * D + fo);
        mn[0] = b2f((unsigned short)v.x); mn[1] = b2f((unsigned short)(v.x >> 16));
        mn[2] = b2f((unsigned short)v.y); mn[3] = b2f((unsigned short)(v.y >> 16));
        mn[4] = b2f((unsigned short)v.z); mn[5] = b2f((unsigned short)(v.z >> 16));
        mn[6] = b2f((unsigned short)v.w); mn[7] = b2f((unsigned short)(v.w >> 16));
    }
    const int c = min((int)cnt[node], CAP);
    const unsigned short* pl = packed16 + (unsigned)node * CAP;
    if (c > 0) {
        uint4 v = *(const uint4*)(T16 + (int)pl[0] * D + fo);
        for (int i = 1; i < c; ++i) {
            uint4 vn = *(const uint4*)(T16 + (int)pl[i] * D + fo);  // prefetch next
            MIN8(v);
            v = vn;
        }
        MIN8(v);
    }
    // epilogue: out = C - min
    if (fp32mode) {
        float* Crow = (float*)outv + node * D + fo;
        float4 a = *(const float4*)Crow;
        float4 b = *(const float4*)(Crow + 4);
        a.x -= mn[0]; a.y -= mn[1]; a.z -= mn[2]; a.w -= mn[3];
        b.x -= mn[4]; b.y -= mn[5]; b.z -= mn[6]; b.w -= mn[7];
        *(float4*)Crow = a;
        *(float4*)(Crow + 4) = b;
    } else {
        unsigned short* Crow = (unsigned short*)outv + node * D + fo;
        uint4 cb = *(const uint4*)Crow;
        uint4 o;
        o.x = (unsigned)f2b(b2f((unsigned short)cb.x) - mn[0])
            | ((unsigned)f2b(b2f((unsigned short)(cb.x >> 16)) - mn[1]) << 16);
        o.y = (unsigned)f2b(b2f((unsigned short)cb.y) - mn[2])
            | ((unsigned)f2b(b2f((unsigned short)(cb.y >> 16)) - mn[3]) << 16);
        o.z = (unsigned)f2b(b2f((unsigned short)cb.z) - mn[4])
            | ((unsigned)f2b(b2f((unsigned short)(cb.z >> 16)) - mn[5]) << 16);
        o.w = (unsigned)f2b(b2f((unsigned short)cb.w) - mn[6])
            | ((unsigned)f2b(b2f((unsigned short)(cb.w >> 16)) - mn[7]) << 16);
        *(uint4*)Crow = o;
    }
}

extern "C" void kernel_launch(void* const* d_in, const int* in_sizes, int n_in,
                              void* d_out, int out_size, void* d_ws, size_t ws_size,
                              hipStream_t stream) {
    // ws layout (~13 MB used; ws is ~256 MB):
    char* p = (char*)d_ws;
    unsigned*       flags    = (unsigned*)p;                         // 256 B
    unsigned*       cnt      = (unsigned*)(p + 256);                 // 50000*4 = 200000 -> pad 200704
    unsigned short* packed16 = (unsigned short*)(p + 200960);        // 50000*64*2 = 6.4 MB
    unsigned short* T16      = (unsigned short*)(p + 200960 + 6400000);   // 6.4 MB (16B-aligned)
    unsigned short* WTfrag   = (unsigned short*)(p + 200960 + 12800000);        // 8 KB
    unsigned short* WPfrag   = (unsigned short*)(p + 200960 + 12800000 + 8192); // 8 KB
    float*          bias_sum = (float*)(p + 200960 + 12800000 + 16384);         // 256 B

    setup<<<SETUP_BLKS, 256, 0, stream>>>(d_in[0], d_in[1], d_in[3], d_in[4], d_in[5], d_in[6],
                                          flags, cnt, WTfrag, WPfrag, bias_sum);
    gemm_scatter<<<GEMM_BLKS + NSC, 256, 0, stream>>>(d_in[0], WTfrag, WPfrag, bias_sum,
                                                      d_in[1], d_in[2], flags,
                                                      cnt, packed16, T16, d_out);
    node_min<<<(N_NODES + 31) / 32, 256, 0, stream>>>(cnt, packed16, T16, flags, d_out);
}

// Round 4
// 124.216 us; speedup vs baseline: 1.3986x; 1.3986x over previous
//
#include <hip/hip_runtime.h>
#include <hip/hip_bf16.h>

#define N_NODES 50000
#define N_EDGES 800000
#define D 64
#define NB 1563       // fine buckets: dst>>5 -> 0..1562 (32 nodes/bucket)
#define BCAP 1024     // fixed slots per bucket region (max load ~600)
#define CHUNK_E 2048  // edges per scatter block
#define NSC 391       // ceil(800000/2048)
#define NSTRIP 3125   // N_NODES/16
#define GEMM_BLKS 196 // 196*4 waves * 4 strips = 3136 >= NSTRIP
#define NWAVES 784    // gemm waves
#define SPW 4         // strips per wave
#define MSTR 65       // mn row stride (u32): 65 mod 32 = 1 -> rows rotate banks

typedef __attribute__((ext_vector_type(8))) short short8v;   // 8 bf16 (4 VGPRs)
typedef __attribute__((ext_vector_type(4))) float float4v;   // 4 fp32 acc

// ---------- helpers ----------
__device__ __forceinline__ float b2f(unsigned short h) {
    return __uint_as_float(((unsigned)h) << 16);
}
__device__ __forceinline__ unsigned short f2b(float f) {
    __hip_bfloat16 t = __float2bfloat16(f);
    return *reinterpret_cast<unsigned short*>(&t);
}
__device__ __forceinline__ short f2bs(float f) { return (short)f2b(f); }
// monotonic float<->uint encoding: unsigned min == float min
__device__ __forceinline__ unsigned f2ord(float f) {
    unsigned u = __float_as_uint(f);
    return (u & 0x80000000u) ? ~u : (u | 0x80000000u);
}
__device__ __forceinline__ float ord2f(unsigned o) {
    return __uint_as_float((o & 0x80000000u) ? (o ^ 0x80000000u) : ~o);
}

// ---------- kernel 1: setup (1 block): flags, W->bf16 W^T frags, bias, zero c_cur
__global__ __launch_bounds__(256)
void setup(const void* __restrict__ featv, const void* __restrict__ srcv,
           const void* __restrict__ Wtv, const void* __restrict__ btv,
           const void* __restrict__ Wpv, const void* __restrict__ bpv,
           unsigned* __restrict__ flags, unsigned* __restrict__ c_cur,
           unsigned short* __restrict__ WTfrag, unsigned short* __restrict__ WPfrag,
           float* __restrict__ bias_sum) {
    __shared__ unsigned sf[2];
    const int t = threadIdx.x;
    if (t < 64) {
        const unsigned short* p = (const unsigned short*)featv;
        float x = b2f(p[2 * t]);
        float a = fabsf(x);
        bool insane = !(a <= 64.f) || (x != 0.f && a < 9.3132e-10f);
        unsigned long long m = __ballot(insane);
        if (t == 0) sf[0] = (__popcll(m) >= 8) ? 1u : 0u;
    } else if (t < 128) {
        const int* s32 = (const int*)srcv;
        int v = s32[2 * (t - 64) + 1];
        unsigned long long m = __ballot(v == 0);
        if (t == 64) sf[1] = (__popcll(m) >= 32) ? 1u : 0u;
    }
    __syncthreads();
    const unsigned fp32mode = sf[0];
    if (t < 2) flags[t] = sf[t];
    for (int i = t; i < NB; i += 256) c_cur[i] = 0;     // replaces memsetAsync
#pragma unroll
    for (int i = 0; i < 16; ++i) {
        int e = i * 256 + t;                           // coalesced read
        int k = e >> 6, n = e & 63;
        float vt, vp;
        if (fp32mode) {
            vt = ((const float*)Wtv)[e];
            vp = ((const float*)Wpv)[e];
        } else {
            vt = b2f(((const unsigned short*)Wtv)[e]);
            vp = b2f(((const unsigned short*)Wpv)[e]);
        }
        WTfrag[n * 64 + k] = f2b(vt);                  // Wfrag[n*64+k] = W[k][n]
        WPfrag[n * 64 + k] = f2b(vp);
    }
    if (t < 64) {
        if (fp32mode)
            bias_sum[t] = ((const float*)btv)[t] + ((const float*)bpv)[t];
        else
            bias_sum[t] = b2f(((const unsigned short*)btv)[t])
                        + b2f(((const unsigned short*)bpv)[t]);
    }
}

// ---------- A(X)-fragment load helpers (strip w, lane m,q) ----------
__device__ __forceinline__ void loadA_bf16(const short* F, int w, int m, int q,
                                           short8v& A0, short8v& A1) {
    const short* fr = F + (w * 16 + m) * D + q * 8;
    A0 = *(const short8v*)fr;
    A1 = *(const short8v*)(fr + 32);
}
__device__ __forceinline__ void loadA_raw(const float* F, int w, int m, int q,
                                          float4 r[8]) {
    const float* fr = F + (w * 16 + m) * D + q * 8;
    r[0] = *(const float4*)(fr);      r[1] = *(const float4*)(fr + 4);
    r[2] = *(const float4*)(fr + 32); r[3] = *(const float4*)(fr + 36);
}
__device__ __forceinline__ void cvtA(const float4 r[8], short8v& A0, short8v& A1) {
    A0 = (short8v){f2bs(r[0].x), f2bs(r[0].y), f2bs(r[0].z), f2bs(r[0].w),
                   f2bs(r[1].x), f2bs(r[1].y), f2bs(r[1].z), f2bs(r[1].w)};
    A1 = (short8v){f2bs(r[2].x), f2bs(r[2].y), f2bs(r[2].z), f2bs(r[2].w),
                   f2bs(r[3].x), f2bs(r[3].y), f2bs(r[3].z), f2bs(r[3].w)};
}

// ---------- kernel 2: fused [MFMA node transforms ∥ bucket append] ----------
// gemm blocks [0, GEMM_BLKS): 4 strips/wave, W-frags hoisted (strip-invariant),
//   A software-pipelined. SWAPPED-operand MFMA (verified round 3):
//   mfma(Wfrag, Xfrag) -> D[feat][node]: lane m owns node w*16+m, regs r hold
//   feats 16c+4q+r -> uint2/float4 stores (4x fewer store instrs than scalar).
// blocks [GEMM_BLKS, +NSC): two-phase append (dst<<16|src) into fixed-stride
//   bucket regions via per-(block,bucket) cursor reservation (proven round 2;
//   per-edge direct global CSR was 3x slower: write amplification + atomic
//   latency chains, round-3 post-mortem). Self-loops dropped.
__global__ __launch_bounds__(256)
void gemm_scatter(const void* __restrict__ featv,
                  const unsigned short* __restrict__ WTfrag,
                  const unsigned short* __restrict__ WPfrag,
                  const float* __restrict__ bias_sum,
                  const void* __restrict__ srcv, const void* __restrict__ dstv,
                  const unsigned* __restrict__ flags,
                  unsigned* __restrict__ c_cur, unsigned* __restrict__ packed,
                  unsigned short* __restrict__ T16, void* __restrict__ outv) {
    const unsigned fp32mode = flags[0];
    if (blockIdx.x < GEMM_BLKS) {
        const int lane = threadIdx.x & 63;
        const int wid  = threadIdx.x >> 6;
        const int wave = blockIdx.x * 4 + wid;         // 0..783
        const int m = lane & 15, q = lane >> 4;

        // hoist all 16 W-frags + bias quads (strip-invariant; L2-hot 16 KB)
        const short8v* BT = (const short8v*)WTfrag;    // idx = feat*8 + half*4 + q
        const short8v* BP = (const short8v*)WPfrag;
        short8v Wt0[4], Wt1[4], Wp0[4], Wp1[4];
        float4 bs4[4];
#pragma unroll
        for (int c = 0; c < 4; ++c) {
            const int col = 16 * c + m;
            Wt0[c] = BT[col * 8 + q];
            Wt1[c] = BT[col * 8 + 4 + q];
            Wp0[c] = BP[col * 8 + q];
            Wp1[c] = BP[col * 8 + 4 + q];
            bs4[c] = *(const float4*)(bias_sum + 16 * c + 4 * q);
        }

        float* Cf  = (float*)outv;
        unsigned short* Ch = (unsigned short*)outv;
        const float* Ff = (const float*)featv;
        const short* Fh = (const short*)featv;

        // software pipeline: load A for strip s+1 while computing strip s
        short8v A0, A1;
        float4 raw[8];
        int w = wave;                                  // strip s=0
        if (fp32mode) { loadA_raw(Ff, min(w, NSTRIP - 1), m, q, raw); cvtA(raw, A0, A1); }
        else          loadA_bf16(Fh, min(w, NSTRIP - 1), m, q, A0, A1);

#pragma unroll
        for (int s = 0; s < SPW; ++s) {
            const int wn = wave + (s + 1) * NWAVES;    // next strip (prefetch)
            if (s + 1 < SPW) {
                if (fp32mode) loadA_raw(Ff, min(wn, NSTRIP - 1), m, q, raw);
                else          loadA_bf16(Fh, min(wn, NSTRIP - 1), m, q, A0, A1);
            }
            if (w < NSTRIP) {
                short8v Acur0, Acur1;
                if (s + 1 < SPW && !fp32mode) {
                    // A0/A1 now hold NEXT; reload current cheaply from L1/L2
                    loadA_bf16(Fh, w, m, q, Acur0, Acur1);
                } else {
                    Acur0 = A0; Acur1 = A1;            // fp32: A holds current
                }
                const int node = w * 16 + m;
                unsigned short* Trow = T16 + node * D;
#pragma unroll
                for (int c = 0; c < 4; ++c) {
                    float4v accT = (float4v){0.f, 0.f, 0.f, 0.f};
                    float4v accP = (float4v){bs4[c].x, bs4[c].y, bs4[c].z, bs4[c].w};
                    // swapped operands: D = W^T x X^T -> D[feat][node]
                    accT = __builtin_amdgcn_mfma_f32_16x16x32_bf16(Wt0[c], Acur0, accT, 0, 0, 0);
                    accT = __builtin_amdgcn_mfma_f32_16x16x32_bf16(Wt1[c], Acur1, accT, 0, 0, 0);
                    accP = __builtin_amdgcn_mfma_f32_16x16x32_bf16(Wp0[c], Acur0, accP, 0, 0, 0);
                    accP = __builtin_amdgcn_mfma_f32_16x16x32_bf16(Wp1[c], Acur1, accP, 0, 0, 0);
                    // D layout: col(lane&15)=node-in-strip, row(q*4+r)=feat
                    const int foff = 16 * c + 4 * q;   // 4 consecutive feats
                    unsigned t0 = (unsigned)f2b(accT[0]) | ((unsigned)f2b(accT[1]) << 16);
                    unsigned t1 = (unsigned)f2b(accT[2]) | ((unsigned)f2b(accT[3]) << 16);
                    *(uint2*)(Trow + foff) = make_uint2(t0, t1);
                    if (fp32mode) {
                        *(float4*)(Cf + node * D + foff) =
                            make_float4(accT[0] + accP[0], accT[1] + accP[1],
                                        accT[2] + accP[2], accT[3] + accP[3]);
                    } else {
                        unsigned c0 = (unsigned)f2b(accT[0] + accP[0])
                                    | ((unsigned)f2b(accT[1] + accP[1]) << 16);
                        unsigned c1 = (unsigned)f2b(accT[2] + accP[2])
                                    | ((unsigned)f2b(accT[3] + accP[3]) << 16);
                        *(uint2*)(Ch + node * D + foff) = make_uint2(c0, c1);
                    }
                }
            }
            w = wn;
            if (fp32mode && s + 1 < SPW) cvtA(raw, A0, A1);  // convert prefetched
        }
    } else {
        // ---- bucket append branch (two-phase, proven round 2) ----
        __shared__ unsigned h[NB];                     // 6.3 KB
        const int t = threadIdx.x;
        for (int i = t; i < NB; i += 256) h[i] = 0;
        __syncthreads();
        const unsigned idx64 = flags[1];
        const int base = (blockIdx.x - GEMM_BLKS) * CHUNK_E;
        unsigned pk[CHUNK_E / 256];
#pragma unroll
        for (int j = 0; j < CHUNK_E / 256; ++j) {
            int e = base + j * 256 + t;
            unsigned p = 0xFFFFFFFFu;                  // sentinel
            if (e < N_EDGES) {
                int s, d;
                if (idx64) {
                    s = (int)((const long long*)srcv)[e];
                    d = (int)((const long long*)dstv)[e];
                } else {
                    s = ((const int*)srcv)[e];
                    d = ((const int*)dstv)[e];
                }
                s = min(max(s, 0), N_NODES - 1);
                d = min(max(d, 0), N_NODES - 1);
                if (s != d) {                          // self-loops seeded in k3
                    p = ((unsigned)d << 16) | (unsigned)s;
                    atomicAdd(&h[d >> 5], 1u);
                }
            }
            pk[j] = p;
        }
        __syncthreads();
        // one reservation atomic per non-empty (block,bucket); h becomes cursor
        for (int i = t; i < NB; i += 256) {
            unsigned c = h[i];
            h[i] = c ? atomicAdd(&c_cur[i], c) : 0u;   // skip zero cells
        }
        __syncthreads();
#pragma unroll
        for (int j = 0; j < CHUNK_E / 256; ++j) {
            unsigned p = pk[j];
            if (p != 0xFFFFFFFFu) {
                unsigned bkt = p >> 21;                // == dst>>5
                unsigned pos = atomicAdd(&h[bkt], 1u);
                if (pos < BCAP)                        // overflow guard (never hits)
                    packed[bkt * BCAP + pos] = p;
            }
        }
    }
}

// ---------- kernel 3: per-bucket LDS-atomic min + fused epilogue ----------
// One block per bucket of 32 nodes. mn[32] rows of 64 ord-u32 minima in LDS at
// row stride 65 (65 mod 32 = 1: random dst rows rotate the bank set). Seeded
// with each node's own T row (covers self-loops). uint4 gathers: 8 lanes x
// 8 shorts (16 B/lane) per T row, 8 edges/wave-instr, 2 gathers in flight.
// 256 thr, launch_bounds(256,8): all 1563 blocks co-resident (8 blocks/CU).
__global__ __launch_bounds__(256, 8)
void bucket_min(const unsigned* __restrict__ c_cur, const unsigned* __restrict__ packed,
                const unsigned short* __restrict__ T16, const unsigned* __restrict__ flags,
                void* __restrict__ outv) {
    __shared__ unsigned mn[32 * MSTR];                 // 8.3 KB
    const unsigned fp32mode = flags[0];
    const int t = threadIdx.x;
    const int b = blockIdx.x;
    const int node0 = b << 5;
    // seed with own-node T rows (coalesced 4 KB; covers self-loop edges)
    for (int sl = t; sl < 32 * 16; sl += 256) {
        const int row = sl >> 4;
        const int f4 = (sl & 15) << 2;
        unsigned* mp = &mn[row * MSTR + f4];
        if (node0 + row < N_NODES) {
            uint2 v = *(const uint2*)(T16 + (node0 + row) * D + f4);
            mp[0] = f2ord(b2f((unsigned short)v.x));
            mp[1] = f2ord(b2f((unsigned short)(v.x >> 16)));
            mp[2] = f2ord(b2f((unsigned short)v.y));
            mp[3] = f2ord(b2f((unsigned short)(v.y >> 16)));
        } else {
            mp[0] = mp[1] = mp[2] = mp[3] = 0xFFFFFFFFu;
        }
    }
    __syncthreads();
    const int cnt = min((int)c_cur[b], BCAP);
    const unsigned* pb = packed + b * BCAP;
    const int lane = t & 63, wv = t >> 6;              // 4 waves
    const int g = lane >> 3;                           // 8 edges per wave instr
    const int fh = (lane & 7) << 3;                    // short idx (8 shorts/lane)
    const int fu = (lane & 7) << 3;                    // u32 idx into mn row
    int i = wv * 8 + g;                                // 32 slots/block
    for (; i + 32 < cnt; i += 64) {                    // 2 gathers in flight
        unsigned p0 = pb[i], p1 = pb[i + 32];
        uint4 v0 = *(const uint4*)(T16 + (int)(p0 & 0xFFFFu) * D + fh);
        uint4 v1 = *(const uint4*)(T16 + (int)(p1 & 0xFFFFu) * D + fh);
        unsigned* m0p = &mn[(int)((p0 >> 16) & 31u) * MSTR + fu];
        unsigned* m1p = &mn[(int)((p1 >> 16) & 31u) * MSTR + fu];
        atomicMin(m0p + 0, f2ord(b2f((unsigned short)v0.x)));
        atomicMin(m0p + 1, f2ord(b2f((unsigned short)(v0.x >> 16))));
        atomicMin(m0p + 2, f2ord(b2f((unsigned short)v0.y)));
        atomicMin(m0p + 3, f2ord(b2f((unsigned short)(v0.y >> 16))));
        atomicMin(m0p + 4, f2ord(b2f((unsigned short)v0.z)));
        atomicMin(m0p + 5, f2ord(b2f((unsigned short)(v0.z >> 16))));
        atomicMin(m0p + 6, f2ord(b2f((unsigned short)v0.w)));
        atomicMin(m0p + 7, f2ord(b2f((unsigned short)(v0.w >> 16))));
        atomicMin(m1p + 0, f2ord(b2f((unsigned short)v1.x)));
        atomicMin(m1p + 1, f2ord(b2f((unsigned short)(v1.x >> 16))));
        atomicMin(m1p + 2, f2ord(b2f((unsigned short)v1.y)));
        atomicMin(m1p + 3, f2ord(b2f((unsigned short)(v1.y >> 16))));
        atomicMin(m1p + 4, f2ord(b2f((unsigned short)v1.z)));
        atomicMin(m1p + 5, f2ord(b2f((unsigned short)(v1.z >> 16))));
        atomicMin(m1p + 6, f2ord(b2f((unsigned short)v1.w)));
        atomicMin(m1p + 7, f2ord(b2f((unsigned short)(v1.w >> 16))));
    }
    for (; i < cnt; i += 32) {
        unsigned p0 = pb[i];
        uint4 v0 = *(const uint4*)(T16 + (int)(p0 & 0xFFFFu) * D + fh);
        unsigned* m0p = &mn[(int)((p0 >> 16) & 31u) * MSTR + fu];
        atomicMin(m0p + 0, f2ord(b2f((unsigned short)v0.x)));
        atomicMin(m0p + 1, f2ord(b2f((unsigned short)(v0.x >> 16))));
        atomicMin(m0p + 2, f2ord(b2f((unsigned short)v0.y)));
        atomicMin(m0p + 3, f2ord(b2f((unsigned short)(v0.y >> 16))));
        atomicMin(m0p + 4, f2ord(b2f((unsigned short)v0.z)));
        atomicMin(m0p + 5, f2ord(b2f((unsigned short)(v0.z >> 16))));
        atomicMin(m0p + 6, f2ord(b2f((unsigned short)v0.w)));
        atomicMin(m0p + 7, f2ord(b2f((unsigned short)(v0.w >> 16))));
    }
    __syncthreads();
    // epilogue: out = C - min for the bucket's 32 nodes
    for (int sl = t; sl < 32 * 16; sl += 256) {
        const int row = sl >> 4;
        const int node = node0 + row;
        if (node >= N_NODES) continue;
        const int f4 = (sl & 15) << 2;
        const unsigned* mp = &mn[row * MSTR + f4];
        float m0 = ord2f(mp[0]), m1 = ord2f(mp[1]);
        float m2 = ord2f(mp[2]), m3 = ord2f(mp[3]);
        if (fp32mode) {
            float4* C = (float4*)((float*)outv + node * D + f4);
            float4 c = *C;
            *C = make_float4(c.x - m0, c.y - m1, c.z - m2, c.w - m3);
        } else {
            unsigned short* C = (unsigned short*)outv + node * D + f4;
            uint2 c = *(uint2*)C;
            unsigned lo = (unsigned)f2b(b2f((unsigned short)c.x) - m0)
                        | ((unsigned)f2b(b2f((unsigned short)(c.x >> 16)) - m1) << 16);
            unsigned hi = (unsigned)f2b(b2f((unsigned short)c.y) - m2)
                        | ((unsigned)f2b(b2f((unsigned short)(c.y >> 16)) - m3) << 16);
            *(uint2*)C = make_uint2(lo, hi);
        }
    }
}

extern "C" void kernel_launch(void* const* d_in, const int* in_sizes, int n_in,
                              void* d_out, int out_size, void* d_ws, size_t ws_size,
                              hipStream_t stream) {
    // ws layout (~12.8 MB used; ws is ~256 MB):
    char* p = (char*)d_ws;
    unsigned*       flags    = (unsigned*)p;                     // 256 B
    unsigned*       c_cur    = (unsigned*)(p + 256);             // 1563*4 -> pad 8192
    unsigned*       packed   = (unsigned*)(p + 8448);            // 1563*1024*4 = 6.40 MB
    unsigned short* T16      = (unsigned short*)(p + 8448 + 6402048);   // 6.4 MB (16B-aligned)
    unsigned short* WTfrag   = (unsigned short*)(p + 8448 + 6402048 + 6400000);        // 8 KB
    unsigned short* WPfrag   = (unsigned short*)(p + 8448 + 6402048 + 6400000 + 8192); // 8 KB
    float*          bias_sum = (float*)(p + 8448 + 6402048 + 6400000 + 16384);         // 256 B

    setup<<<1, 256, 0, stream>>>(d_in[0], d_in[1], d_in[3], d_in[4], d_in[5], d_in[6],
                                 flags, c_cur, WTfrag, WPfrag, bias_sum);
    gemm_scatter<<<GEMM_BLKS + NSC, 256, 0, stream>>>(d_in[0], WTfrag, WPfrag, bias_sum,
                                                      d_in[1], d_in[2], flags,
                                                      c_cur, packed, T16, d_out);
    bucket_min<<<NB, 256, 0, stream>>>(c_cur, packed, T16, flags, d_out);
}